// Round 8
// baseline (323.177 us; speedup 1.0000x reference)
//
#include <hip/hip_runtime.h>

#define BATCH 16
#define CIN   200
#define T1    8192
#define COUTC 400
#define TT2   4096
#define NJ    25
#define NGROUP 10
#define CPG   40
#define NPOOL 14
#define CPAD  216
#define NFRAG 117

typedef __attribute__((ext_vector_type(8))) short bf16x8;
typedef __attribute__((ext_vector_type(4))) float f32x4;

__constant__ int NBR_OFF[NJ + 1] = {0,8,14,18,21,29,35,39,42,50,56,63,72,80,85,94,101,106,110,113,122,129,134,138,141,145};
__constant__ int NBR[145] = {
 0,1,2,4,5,8,9,24,
 0,1,2,3,4,8,
 0,1,2,3,
 1,2,3,
 0,1,4,5,6,8,9,24,
 0,4,5,6,7,8,
 4,5,6,7,
 5,6,7,
 0,1,4,5,8,9,10,24,
 0,4,8,9,10,11,
 8,9,10,11,12,14,19,
 9,10,11,12,13,14,15,19,20,
 10,11,12,13,14,15,19,20,
 11,12,13,14,19,
 10,11,12,13,14,15,16,19,20,
 11,12,14,15,16,17,19,
 14,15,16,17,18,
 15,16,17,18,
 16,17,18,
 10,11,12,13,14,15,19,20,21,
 11,12,14,19,20,21,22,
 19,20,21,22,23,
 20,21,22,23,
 21,22,23,
 0,4,8,24};
__constant__ int PAIR_A[NPOOL] = {0,2,4,6,8,10,12,14,15,17,19,20,22,24};
__constant__ int PAIR_B[NPOOL] = {1,3,5,7,9,11,13,-1,16,18,-1,21,23,-1};
__constant__ int JORD[NJ] = {11,14,19,0,4,8,12,10,15,20,1,5,9,13,16,21,2,6,17,22,24,3,7,18,23};
// mfma fragment tables: nmf[jo]=ceil(3*deg/4), FBASE=prefix sum, FRAG_JO inverse map
__constant__ int NMF[NJ]   = {6,5,3,3,6,5,3,3,6,5,6,7,6,4,7,6,4,3,3,7,6,4,3,3,3};
__constant__ int FBASE[NJ] = {0,6,11,14,17,23,28,31,34,40,45,51,58,64,68,75,81,85,88,91,98,104,108,111,114};
__constant__ int FRAG_JO[NFRAG] = {
 0,0,0,0,0,0, 1,1,1,1,1, 2,2,2, 3,3,3, 4,4,4,4,4,4, 5,5,5,5,5, 6,6,6, 7,7,7,
 8,8,8,8,8,8, 9,9,9,9,9, 10,10,10,10,10,10, 11,11,11,11,11,11,11, 12,12,12,12,12,12,
 13,13,13,13, 14,14,14,14,14,14,14, 15,15,15,15,15,15, 16,16,16,16, 17,17,17, 18,18,18,
 19,19,19,19,19,19,19, 20,20,20,20,20,20, 21,21,21,21, 22,22,22, 23,23,23, 24,24,24};

// ---- bf16 helpers (RNE pack, shift unpack) ----
__device__ __forceinline__ unsigned bfround(float f) {
    unsigned u = __builtin_bit_cast(unsigned, f);
    return (u + 0x7FFFu + ((u >> 16) & 1u)) >> 16;
}
__device__ __forceinline__ unsigned packbf(float lo, float hi) {
    return bfround(lo) | (bfround(hi) << 16);
}
__device__ __forceinline__ float bflo(unsigned u) { return __builtin_bit_cast(float, u << 16); }
__device__ __forceinline__ float bfhi(unsigned u) { return __builtin_bit_cast(float, u & 0xFFFF0000u); }

// ------- Kernel A: conv0 (K=3,s=1,reflect)+PReLU + shortcut (K=1,s=2), prefetch --
// grid (8, 25, 16), block 256, 4 t/thread.  h0b bf16 (B,200,8192); sb bf16 (B,400,4096)
__global__ __launch_bounds__(256) void conv0j4(
    const float* __restrict__ x, const float* __restrict__ w0,
    const float* __restrict__ b0, const float* __restrict__ a0,
    const float* __restrict__ wsc, const float* __restrict__ bsc,
    unsigned* __restrict__ h0b, unsigned* __restrict__ sb)
{
    const int jo  = JORD[blockIdx.y];
    const int b   = blockIdx.z;
    const int tid = threadIdx.x;
    const int t0  = (blockIdx.x * 256 + tid) * 4;

    const int off = NBR_OFF[jo];
    const int n8  = (NBR_OFF[jo + 1] - off) * 8;

    __shared__ float wl[72 * 24];
    __shared__ float wsl[72 * 16];
    __shared__ int   cil[72];
    __shared__ float bl[8], bsl[16];

    for (int i = tid; i < n8; i += 256)
        cil[i] = NBR[off + (i >> 3)] * 8 + (i & 7);
    for (int idx = tid; idx < n8 * 24; idx += 256) {
        int cl = idx / 24; int r = idx - cl * 24; int k = r >> 3; int oc = r & 7;
        int ci = NBR[off + (cl >> 3)] * 8 + (cl & 7);
        wl[idx] = w0[(size_t)(jo * 8 + oc) * 600 + ci * 3 + k];
    }
    for (int idx = tid; idx < n8 * 16; idx += 256) {
        int cl = idx >> 4; int c = idx & 15;
        int ci = NBR[off + (cl >> 3)] * 8 + (cl & 7);
        wsl[idx] = wsc[(size_t)(jo * 16 + c) * 200 + ci];
    }
    if (tid < 8)  bl[tid]  = b0[jo * 8 + tid];
    if (tid < 16) bsl[tid] = bsc[jo * 16 + tid];
    __syncthreads();

    const float alpha = a0[0];
    const bool first = (t0 == 0);
    const bool last  = (t0 + 4 == T1);
    const int idx_m = first ? 1 : t0 - 1;
    const int idx_p = last ? (T1 - 2) : t0 + 4;
    const float* xb = x + (size_t)b * CIN * T1;

    float acc[8][4];
#pragma unroll
    for (int oc = 0; oc < 8; ++oc) {
        float bv = bl[oc];
#pragma unroll
        for (int i = 0; i < 4; ++i) acc[oc][i] = bv;
    }
    float sacc[16][2];
#pragma unroll
    for (int c = 0; c < 16; ++c) { sacc[c][0] = bsl[c]; sacc[c][1] = bsl[c]; }

    const float* xc0 = xb + (size_t)cil[0] * T1;
    float4 v  = *(const float4*)(xc0 + t0);
    float  xm = xc0[idx_m];
    float  xp = xc0[idx_p];

    for (int cl = 0; cl < n8; ++cl) {
        float4 vc = v; float xmc = xm, xpc = xp;
        if (cl + 1 < n8) {
            const float* xn = xb + (size_t)cil[cl + 1] * T1;
            v  = *(const float4*)(xn + t0);
            xm = xn[idx_m];
            xp = xn[idx_p];
        }
        float xs[6] = {xmc, vc.x, vc.y, vc.z, vc.w, xpc};
        const float* wrow = &wl[cl * 24];
#pragma unroll
        for (int k = 0; k < 3; ++k) {
            float wv[8];
            *(float4*)(wv)     = *(const float4*)(wrow + k * 8);
            *(float4*)(wv + 4) = *(const float4*)(wrow + k * 8 + 4);
#pragma unroll
            for (int oc = 0; oc < 8; ++oc)
#pragma unroll
                for (int i = 0; i < 4; ++i)
                    acc[oc][i] += wv[oc] * xs[i + k];
        }
        const float* wsr = &wsl[cl * 16];
#pragma unroll
        for (int q = 0; q < 4; ++q) {
            float wsv[4];
            *(float4*)(wsv) = *(const float4*)(wsr + 4 * q);
#pragma unroll
            for (int c = 0; c < 4; ++c) {
                sacc[4 * q + c][0] += wsv[c] * vc.x;
                sacc[4 * q + c][1] += wsv[c] * vc.z;
            }
        }
    }

    unsigned* hb = h0b + ((size_t)b * CIN + jo * 8) * (T1 / 2) + t0 / 2;
#pragma unroll
    for (int oc = 0; oc < 8; ++oc) {
        float v0 = acc[oc][0] >= 0.f ? acc[oc][0] : alpha * acc[oc][0];
        float v1 = acc[oc][1] >= 0.f ? acc[oc][1] : alpha * acc[oc][1];
        float v2 = acc[oc][2] >= 0.f ? acc[oc][2] : alpha * acc[oc][2];
        float v3 = acc[oc][3] >= 0.f ? acc[oc][3] : alpha * acc[oc][3];
        uint2 o; o.x = packbf(v0, v1); o.y = packbf(v2, v3);
        *(uint2*)(hb + (size_t)oc * (T1 / 2)) = o;
    }

    unsigned* sbp = sb + ((size_t)b * COUTC + jo * 16) * (TT2 / 2) + t0 / 4;
#pragma unroll
    for (int c = 0; c < 16; ++c)
        sbp[(size_t)c * (TT2 / 2)] = packbf(sacc[c][0], sacc[c][1]);
}

// ------- Kernel W: prepack conv1 weights into per-fragment lane layout -----------
// grid (117), block 256. wA[f][lane][j] bf16: A[m=lane&15][k=(lane>>4)*8+j] of chunk mf
__global__ void wprep1(const float* __restrict__ w1, unsigned short* __restrict__ wA)
{
    const int f  = blockIdx.x;
    const int jo = FRAG_JO[f];
    const int mf = f - FBASE[jo];
    const int off = NBR_OFF[jo];
    const int deg = NBR_OFF[jo + 1] - off;
    for (int e = threadIdx.x; e < 512; e += 256) {
        int lane = e >> 3, j = e & 7;
        int m = lane & 15, kb = lane >> 4;
        int c8 = mf * 4 + kb;
        float v = 0.f;
        if (c8 < 3 * deg) {
            int tap = (c8 >= 2 * deg) ? 2 : ((c8 >= deg) ? 1 : 0);
            int nbr_i = c8 - tap * deg;
            int ci = NBR[off + nbr_i] * 8 + j;
            v = w1[(size_t)(jo * 16 + m) * 600 + ci * 3 + tap];
        }
        wA[(size_t)f * 512 + e] = (unsigned short)bfround(v);
    }
}

// ------- Kernel B: conv1 via MFMA 16x16x32 bf16 + GN partials --------------------
// grid (64, 16), block 256 (4 waves x 16 t2).  h1u u16-bf16 (B,400,4096)
// LDS x-tile: odd rows O[65][CPAD] then even rows E[64][CPAD] (p parity split)
__global__ __launch_bounds__(256) void conv1_mfma(
    const unsigned* __restrict__ h0b, const unsigned short* __restrict__ wA,
    const float* __restrict__ b1, unsigned short* __restrict__ h1u,
    float* __restrict__ part)
{
    __shared__ unsigned short xs[(65 + 64) * CPAD];   // 55.7 KB
    __shared__ float biasl[COUTC];
    __shared__ int   nbrl[145];
    const int b   = blockIdx.y;
    const int t20 = blockIdx.x * 64;
    const int tid = threadIdx.x;

    for (int i = tid; i < 145; i += 256) nbrl[i] = NBR[i];
    for (int i = tid; i < COUTC; i += 256) biasl[i] = b1[i];

    // stage: uint gi holds h0 at p=2gi (lo -> even array) and p=2gi+1 (hi -> odd)
    // O[k] = h0[2*t20-1+2k] (reflect handled by clamp), E[k] = h0[2*t20+2k]
    const unsigned* hb = h0b + (size_t)b * CIN * (T1 / 2);
    for (int e = tid; e < CIN * 65; e += 256) {
        int c = e / 65, i = e - c * 65;
        int gi = t20 - 1 + i; if (gi < 0) gi = 0;   // clamp: O[0]=h0[1] = reflect
        unsigned u = hb[(size_t)c * (T1 / 2) + gi];
        xs[i * CPAD + c] = (unsigned short)(u >> 16);            // odd row i
        if (i > 0)
            xs[(65 + i - 1) * CPAD + c] = (unsigned short)(u & 0xFFFF); // even row i-1
    }
    __syncthreads();

    const int w = tid >> 6, lane = tid & 63;
    const int q = lane >> 4, n = lane & 15;
    const int t2l = w * 16 + n;
    const int t2g = t20 + t2l;

    for (int jo = 0; jo < NJ; ++jo) {
        const int off = NBR_OFF[jo];
        const int deg = NBR_OFF[jo + 1] - off;
        const int fb  = FBASE[jo];
        const int nmf = NMF[jo];
        f32x4 acc = {0.f, 0.f, 0.f, 0.f};

        bf16x8 a = *(const bf16x8*)(wA + ((size_t)fb * 64 + lane) * 8);
        for (int mf = 0; mf < nmf; ++mf) {
            bf16x8 acur = a;
            if (mf + 1 < nmf)
                a = *(const bf16x8*)(wA + ((size_t)(fb + mf + 1) * 64 + lane) * 8);
            int c8 = mf * 4 + q;
            int tap = (c8 >= 2 * deg) ? 2 : ((c8 >= deg) ? 1 : 0);
            int nbr_i = c8 - tap * deg;
            if (c8 >= 3 * deg) { tap = 0; nbr_i = 0; }   // pad chunk: A=0, B=finite
            int col = nbrl[off + nbr_i] * 8;
            // p = 2*t2+tap-1: tap==1 -> even array (offset 65*CPAD, row t2l);
            // tap 0/2 -> odd array (row t2l + tap/2)
            int base = (tap == 1) ? 65 * CPAD : 0;
            int row  = t2l + (tap >> 1);
            bf16x8 bv = *(const bf16x8*)(xs + base + row * CPAD + col);
            acc = __builtin_amdgcn_mfma_f32_16x16x32_bf16(acur, bv, acc, 0, 0, 0);
        }

        // epilogue: bias, GN partials, bf16 store.  C: col=lane&15 (t2), row=q*4+r (oc)
        float s = 0.f, ss = 0.f;
        unsigned short* hout = h1u + ((size_t)b * COUTC + jo * 16) * TT2 + t2g;
#pragma unroll
        for (int r = 0; r < 4; ++r) {
            int oc = q * 4 + r;
            float v = acc[r] + biasl[jo * 16 + oc];
            s += v; ss += v * v;
            hout[(size_t)oc * TT2] = (unsigned short)bfround(v);
        }
        // lanes 0..31 hold oc 0..7 (half 0), lanes 32..63 oc 8..15 (half 1)
        for (int o2 = 1; o2 < 32; o2 <<= 1) {
            s  += __shfl_xor(s, o2, 64);
            ss += __shfl_xor(ss, o2, 64);
        }
        if ((lane & 31) == 0) {
            int half = lane >> 5;
            size_t o = ((((size_t)b * 50 + jo * 2 + half) * 64 + blockIdx.x) * 4 + w) * 2;
            part[o] = s; part[o + 1] = ss;
        }
    }
}

// ------- Kernel C: finalize stats (one block per (b,g)) --------------------------
__global__ __launch_bounds__(256) void gn_final2(const float* __restrict__ part,
                                                 float* __restrict__ stats)
{
    const int bg = blockIdx.x;
    const int b = bg / NGROUP, g = bg % NGROUP;
    float s = 0.f, ss = 0.f;
    for (int k = threadIdx.x; k < 5 * 256; k += 256) {
        int sb = k >> 8, slot = k & 255;
        size_t o = (((size_t)b * 50 + g * 5 + sb) * 256 + slot) * 2;
        s += part[o]; ss += part[o + 1];
    }
    for (int o2 = 32; o2; o2 >>= 1) {
        s  += __shfl_down(s, o2, 64);
        ss += __shfl_down(ss, o2, 64);
    }
    __shared__ float rs[4], rss[4];
    const int lane = threadIdx.x & 63, wv = threadIdx.x >> 6;
    if (lane == 0) { rs[wv] = s; rss[wv] = ss; }
    __syncthreads();
    if (threadIdx.x == 0) {
        float S  = rs[0] + rs[1] + rs[2] + rs[3];
        float SS = rss[0] + rss[1] + rss[2] + rss[3];
        const float invN = 1.0f / (float)(CPG * TT2);
        float mean = S * invN;
        float var  = SS * invN - mean * mean;
        stats[bg * 2]     = mean;
        stats[bg * 2 + 1] = rsqrtf(var + 1e-5f);
    }
}

// ------- Kernel D: per-(b,ch) GN coefficients ------------------------------------
__global__ void gn_coef(const float* __restrict__ stats, const float* __restrict__ gamma,
                        const float* __restrict__ beta, float* __restrict__ AB)
{
    int idx = blockIdx.x * 256 + threadIdx.x;
    if (idx < BATCH * COUTC) {
        int b = idx / COUTC; int ch = idx - b * COUTC;
        int g = ch / CPG;
        float m = stats[(b * NGROUP + g) * 2];
        float r = stats[(b * NGROUP + g) * 2 + 1];
        float A = r * gamma[ch];
        AB[(size_t)idx * 2]     = A;
        AB[(size_t)idx * 2 + 1] = beta[ch] - m * A;
    }
}

// ------- Kernel E: streaming GN-apply + add s + pool + PReLU ---------------------
// grid (4, 28, 16), block 256, 4 t2/thread
__global__ __launch_bounds__(256) void final2pb(
    const unsigned* __restrict__ h1b, const unsigned* __restrict__ sb,
    const float* __restrict__ AB, const float* __restrict__ a1,
    float* __restrict__ outb)
{
    const int n     = blockIdx.y >> 1;
    const int chalf = blockIdx.y & 1;
    const int b     = blockIdx.z;
    const int tid   = threadIdx.x;
    const int t0    = (blockIdx.x * 256 + tid) * 4;

    int js[2];
    js[0] = PAIR_A[n];
    const int jb = PAIR_B[n];
    const int L = (jb >= 0) ? 2 : 1;
    js[1] = (jb >= 0) ? jb : js[0];

    __shared__ float Al[2][8], Bl[2][8];
    if (tid < 16) {
        int ji = tid >> 3, c8 = tid & 7;
        int ch = js[ji] * 16 + chalf * 8 + c8;
        Al[ji][c8] = AB[((size_t)b * COUTC + ch) * 2];
        Bl[ji][c8] = AB[((size_t)b * COUTC + ch) * 2 + 1];
    }
    __syncthreads();

    const float alpha = a1[0];
    const float invL  = (L == 2) ? 0.5f : 1.0f;

    float acc[8][4];
#pragma unroll
    for (int c = 0; c < 8; ++c)
#pragma unroll
        for (int i = 0; i < 4; ++i) acc[c][i] = 0.f;

    for (int ji = 0; ji < L; ++ji) {
        const int jc0 = js[ji] * 16 + chalf * 8;
#pragma unroll
        for (int c = 0; c < 8; ++c) {
            size_t rowoff = ((size_t)b * COUTC + jc0 + c) * (TT2 / 2) + t0 / 2;
            uint2 hv = *(const uint2*)(h1b + rowoff);
            uint2 sv = *(const uint2*)(sb + rowoff);
            float A = Al[ji][c], Bc = Bl[ji][c];
            acc[c][0] += bflo(hv.x) * A + Bc + bflo(sv.x);
            acc[c][1] += bfhi(hv.x) * A + Bc + bfhi(sv.x);
            acc[c][2] += bflo(hv.y) * A + Bc + bflo(sv.y);
            acc[c][3] += bfhi(hv.y) * A + Bc + bfhi(sv.y);
        }
    }

    float* ob = outb + ((size_t)b * 224 + n * 16 + chalf * 8) * TT2 + t0;
#pragma unroll
    for (int c = 0; c < 8; ++c) {
        float4 o;
#pragma unroll
        for (int i = 0; i < 4; ++i) {
            float v = acc[c][i] * invL;
            ((float*)&o)[i] = (v >= 0.f) ? v : alpha * v;
        }
        *(float4*)(ob + (size_t)c * TT2) = o;
    }
}

extern "C" void kernel_launch(void* const* d_in, const int* in_sizes, int n_in,
                              void* d_out, int out_size, void* d_ws, size_t ws_size,
                              hipStream_t stream) {
    const float* x     = (const float*)d_in[0];
    const float* w0    = (const float*)d_in[1];
    const float* b0    = (const float*)d_in[2];
    const float* a0    = (const float*)d_in[3];
    const float* w1    = (const float*)d_in[4];
    const float* b1    = (const float*)d_in[5];
    const float* gamma = (const float*)d_in[6];
    const float* beta  = (const float*)d_in[7];
    const float* wsc   = (const float*)d_in[8];
    const float* bsc   = (const float*)d_in[9];
    const float* a1    = (const float*)d_in[10];
    float* out = (float*)d_out;

    unsigned* h0b = (unsigned*)d_ws;                            // 13,107,200 uint
    unsigned* sbf = h0b + (size_t)BATCH * CIN * (T1 / 2);       // 13,107,200 uint
    unsigned* h1b = sbf + (size_t)BATCH * COUTC * (TT2 / 2);    // 13,107,200 uint
    unsigned* wAu = h1b + (size_t)BATCH * COUTC * (TT2 / 2);    // 29,952 uint (117*512 u16)
    float* part   = (float*)(wAu + NFRAG * 256);                // 16*50*256*2 = 409,600 f32
    float* stats  = part + (size_t)BATCH * 50 * 256 * 2;        // 320
    float* AB     = stats + BATCH * NGROUP * 2;                 // 12,800

    wprep1<<<dim3(NFRAG), 256, 0, stream>>>(w1, (unsigned short*)wAu);
    conv0j4<<<dim3(T1 / 1024, NJ, BATCH), 256, 0, stream>>>(x, w0, b0, a0, wsc, bsc, h0b, sbf);
    conv1_mfma<<<dim3(TT2 / 64, BATCH), 256, 0, stream>>>(h0b, (const unsigned short*)wAu, b1,
                                                          (unsigned short*)h1b, part);
    gn_final2<<<dim3(BATCH * NGROUP), 256, 0, stream>>>(part, stats);
    gn_coef<<<dim3(25), 256, 0, stream>>>(stats, gamma, beta, AB);
    final2pb<<<dim3(TT2 / 1024, NPOOL * 2, BATCH), 256, 0, stream>>>(h1b, sbf, AB, a1, out);
}

// Round 10
// 315.776 us; speedup vs baseline: 1.0234x; 1.0234x over previous
//
#include <hip/hip_runtime.h>

#define BATCH 16
#define CIN   200
#define T1    8192
#define COUTC 400
#define TT2   4096
#define NJ    25
#define NGROUP 10
#define CPG   40
#define NPOOL 14
#define CPAD  216
#define NFRAG 117
#define XROWB 512      // 256 u16 per row (swizzle-safe: max offset 398^112=510)

typedef __attribute__((ext_vector_type(8))) short bf16x8;
typedef __attribute__((ext_vector_type(4))) float f32x4;

__constant__ int NBR_OFF[NJ + 1] = {0,8,14,18,21,29,35,39,42,50,56,63,72,80,85,94,101,106,110,113,122,129,134,138,141,145};
__constant__ int NBR[145] = {
 0,1,2,4,5,8,9,24,
 0,1,2,3,4,8,
 0,1,2,3,
 1,2,3,
 0,1,4,5,6,8,9,24,
 0,4,5,6,7,8,
 4,5,6,7,
 5,6,7,
 0,1,4,5,8,9,10,24,
 0,4,8,9,10,11,
 8,9,10,11,12,14,19,
 9,10,11,12,13,14,15,19,20,
 10,11,12,13,14,15,19,20,
 11,12,13,14,19,
 10,11,12,13,14,15,16,19,20,
 11,12,14,15,16,17,19,
 14,15,16,17,18,
 15,16,17,18,
 16,17,18,
 10,11,12,13,14,15,19,20,21,
 11,12,14,19,20,21,22,
 19,20,21,22,23,
 20,21,22,23,
 21,22,23,
 0,4,8,24};
__constant__ int PAIR_A[NPOOL] = {0,2,4,6,8,10,12,14,15,17,19,20,22,24};
__constant__ int PAIR_B[NPOOL] = {1,3,5,7,9,11,13,-1,16,18,-1,21,23,-1};
// conv1 fragment tables
__constant__ int NMF[NJ]   = {6,5,3,3,6,5,3,3,6,5,6,7,6,4,7,6,4,3,3,7,6,4,3,3,3};
__constant__ int FBASE[NJ] = {0,6,11,14,17,23,28,31,34,40,45,51,58,64,68,75,81,85,88,91,98,104,108,111,114};
__constant__ int FRAG_JO[NFRAG] = {
 0,0,0,0,0,0, 1,1,1,1,1, 2,2,2, 3,3,3, 4,4,4,4,4,4, 5,5,5,5,5, 6,6,6, 7,7,7,
 8,8,8,8,8,8, 9,9,9,9,9, 10,10,10,10,10,10, 11,11,11,11,11,11,11, 12,12,12,12,12,12,
 13,13,13,13, 14,14,14,14,14,14,14, 15,15,15,15,15,15, 16,16,16,16, 17,17,17, 18,18,18,
 19,19,19,19,19,19,19, 20,20,20,20,20,20, 21,21,21,21, 22,22,22, 23,23,23, 24,24,24};
// conv0 pair-union tables
__constant__ int PUOFF[15] = {0,9,13,22,26,35,45,53,62,70,74,83,91,95,99};
__constant__ int PU[99] = {
 0,1,2,3,4,5,8,9,24,
 0,1,2,3,
 0,1,4,5,6,7,8,9,24,
 4,5,6,7,
 0,1,4,5,8,9,10,11,24,
 8,9,10,11,12,13,14,15,19,20,
 10,11,12,13,14,15,19,20,
 10,11,12,13,14,15,16,19,20,
 11,12,14,15,16,17,18,19,
 15,16,17,18,
 10,11,12,13,14,15,19,20,21,
 11,12,14,19,20,21,22,23,
 20,21,22,23,
 0,4,8,24};
__constant__ int PNMF[NPOOL] = {7,3,7,3,7,8,6,7,6,3,7,6,3,3};
__constant__ int FB0[NPOOL]  = {0,7,10,17,20,27,35,41,48,54,57,64,70,73};  // total 76
__constant__ int FRAG_P[76] = {
 0,0,0,0,0,0,0, 1,1,1, 2,2,2,2,2,2,2, 3,3,3, 4,4,4,4,4,4,4, 5,5,5,5,5,5,5,5,
 6,6,6,6,6,6, 7,7,7,7,7,7,7, 8,8,8,8,8,8, 9,9,9, 10,10,10,10,10,10,10,
 11,11,11,11,11,11, 12,12,12, 13,13,13};
// shortcut fragment tables
__constant__ int NSF[NJ] = {2,2,1,1,2,2,1,1,2,2,2,3,2,2,3,2,2,1,1,3,2,2,1,1,1};
__constant__ int FBS[NJ] = {0,2,4,5,6,8,10,11,12,14,16,18,21,23,25,28,30,32,33,34,37,39,41,42,43}; // total 44
__constant__ int FRAG_SJ[44] = {
 0,0, 1,1, 2, 3, 4,4, 5,5, 6, 7, 8,8, 9,9, 10,10, 11,11,11, 12,12, 13,13,
 14,14,14, 15,15, 16,16, 17, 18, 19,19,19, 20,20, 21,21, 22, 23, 24};

// ---- bf16 helpers ----
__device__ __forceinline__ unsigned bfround(float f) {
    unsigned u = __builtin_bit_cast(unsigned, f);
    return (u + 0x7FFFu + ((u >> 16) & 1u)) >> 16;
}
__device__ __forceinline__ float bflo(unsigned u) { return __builtin_bit_cast(float, u << 16); }
__device__ __forceinline__ float bfhi(unsigned u) { return __builtin_bit_cast(float, u & 0xFFFF0000u); }
__device__ __forceinline__ int xswz(int row) { return ((row + (row >> 3)) & 7) << 4; }

// ------- prepack conv1 weights: wA1[f][lane][j] = A[m=lane&15][k=(lane>>4)*8+j] ---
__global__ void wprep1(const float* __restrict__ w1, unsigned short* __restrict__ wA)
{
    const int f  = blockIdx.x;
    const int jo = FRAG_JO[f];
    const int mf = f - FBASE[jo];
    const int off = NBR_OFF[jo];
    const int deg = NBR_OFF[jo + 1] - off;
    for (int e = threadIdx.x; e < 512; e += 256) {
        int lane = e >> 3, j = e & 7;
        int m = lane & 15, kb = lane >> 4;
        int c8 = mf * 4 + kb;
        float v = 0.f;
        if (c8 < 3 * deg) {
            int tap = (c8 >= 2 * deg) ? 2 : ((c8 >= deg) ? 1 : 0);
            int nbr_i = c8 - tap * deg;
            int ci = NBR[off + nbr_i] * 8 + j;
            v = w1[(size_t)(jo * 16 + m) * 600 + ci * 3 + tap];
        }
        wA[(size_t)f * 512 + e] = (unsigned short)bfround(v);
    }
}

// ------- prepack conv0 pair weights (M=16 = two joints' 8 oc, union k-list) ------
__global__ void wprep0(const float* __restrict__ w0, unsigned short* __restrict__ wA)
{
    const int f  = blockIdx.x;
    const int p  = FRAG_P[f];
    const int mf = f - FB0[p];
    const int puo = PUOFF[p];
    const int u   = PUOFF[p + 1] - puo;
    for (int e = threadIdx.x; e < 512; e += 256) {
        int lane = e >> 3, j = e & 7;
        int m = lane & 15, kb = lane >> 4;
        int c8 = mf * 4 + kb;
        int jm = (m < 8) ? PAIR_A[p] : PAIR_B[p];
        float v = 0.f;
        if (c8 < 3 * u && jm >= 0) {
            int tap = (c8 >= 2 * u) ? 2 : ((c8 >= u) ? 1 : 0);
            int ni  = c8 - tap * u;
            int nbr = PU[puo + ni];
            int offj = NBR_OFF[jm], degj = NBR_OFF[jm + 1] - offj;
            bool mem = false;
            for (int s = 0; s < degj; ++s) mem = mem || (NBR[offj + s] == nbr);
            if (mem) {
                int ci = nbr * 8 + j;
                v = w0[(size_t)(jm * 8 + (m & 7)) * 600 + ci * 3 + tap];
            }
        }
        wA[(size_t)f * 512 + e] = (unsigned short)bfround(v);
    }
}

// ------- prepack shortcut weights (M=16 sc channels of one joint) ----------------
__global__ void wprepS(const float* __restrict__ wsc, unsigned short* __restrict__ wA)
{
    const int f  = blockIdx.x;
    const int jo = FRAG_SJ[f];
    const int mf = f - FBS[jo];
    const int off = NBR_OFF[jo];
    const int deg = NBR_OFF[jo + 1] - off;
    for (int e = threadIdx.x; e < 512; e += 256) {
        int lane = e >> 3, j = e & 7;
        int m = lane & 15, kb = lane >> 4;
        int c8 = mf * 4 + kb;
        float v = 0.f;
        if (c8 < deg) {
            int ci = NBR[off + c8] * 8 + j;
            v = wsc[(size_t)(jo * 16 + m) * 200 + ci];
        }
        wA[(size_t)f * 512 + e] = (unsigned short)bfround(v);
    }
}

// ------- Kernel A: conv0 (K=3,s=1,reflect)+PReLU + shortcut (K=1,s=2) via MFMA ---
// grid (128, 16), block 256 (4 waves). LDS x-tile 66 rows x 256 u16 (swizzled), 33 KB.
__global__ __launch_bounds__(256) void conv0s_mfma(
    const float* __restrict__ x, const unsigned short* __restrict__ wA0,
    const unsigned short* __restrict__ wAs, const float* __restrict__ b0,
    const float* __restrict__ a0, const float* __restrict__ bsc,
    unsigned short* __restrict__ h0u, unsigned short* __restrict__ sbu)
{
    __shared__ __align__(16) unsigned short xs[66 * 256];
    const int b   = blockIdx.y;
    const int t0  = blockIdx.x * 64;
    const int tid = threadIdx.x;
    const float* xb = x + (size_t)b * CIN * T1;

    // stage x rows i=0..65 (x pos t0-1+i, reflect-clamped), bf16, swizzled
    for (int e = tid; e < CIN * 33; e += 256) {
        int c = e / 33, i2 = e - c * 33;
        int i = 2 * i2;
        int gp0 = t0 - 1 + i;
        int gp1 = gp0 + 1;
        gp0 = (gp0 < 0) ? 1 : ((gp0 >= T1) ? (2 * T1 - 2 - gp0) : gp0);
        if (gp1 >= T1) gp1 = 2 * T1 - 2 - gp1;
        unsigned short va = (unsigned short)bfround(xb[(size_t)c * T1 + gp0]);
        unsigned short vb = (unsigned short)bfround(xb[(size_t)c * T1 + gp1]);
        *(unsigned short*)((char*)xs + i * XROWB + ((2 * c) ^ xswz(i)))           = va;
        *(unsigned short*)((char*)xs + (i + 1) * XROWB + ((2 * c) ^ xswz(i + 1))) = vb;
    }
    __syncthreads();

    const int w = tid >> 6, lane = tid & 63;
    const int q = lane >> 4, n = lane & 15;
    const float alpha = a0[0];

    // ---- conv0: wave w owns t-subtile [t0+16w, t0+16w+16) ----
    const int tb = w * 16;
    for (int p = 0; p < NPOOL; ++p) {
        const int puo = PUOFF[p];
        const int u   = PUOFF[p + 1] - puo;
        const int fb  = FB0[p], nmf = PNMF[p];
        f32x4 acc = {0.f, 0.f, 0.f, 0.f};
        bf16x8 a = *(const bf16x8*)(wA0 + ((size_t)fb * 64 + lane) * 8);
        // chunk 0: c8=q < u always (u>=4)
        int row0 = tb + n;
        bf16x8 bv = *(const bf16x8*)((char*)xs + row0 * XROWB + ((PU[puo + q] * 16) ^ xswz(row0)));
        for (int mf = 0; mf < nmf; ++mf) {
            int mfn = (mf + 1 < nmf) ? mf + 1 : mf;
            bf16x8 an = *(const bf16x8*)(wA0 + ((size_t)(fb + mfn) * 64 + lane) * 8);
            int c8 = mfn * 4 + q;
            int tp = (c8 >= 2 * u) ? 2 : ((c8 >= u) ? 1 : 0);
            int ni = c8 - tp * u;
            if (c8 >= 3 * u) { tp = 0; ni = 0; }
            int rw = tb + n + tp;
            bf16x8 bn = *(const bf16x8*)((char*)xs + rw * XROWB + ((PU[puo + ni] * 16) ^ xswz(rw)));
            acc = __builtin_amdgcn_mfma_f32_16x16x32_bf16(a, bv, acc, 0, 0, 0);
            a = an; bv = bn;
        }
        int jm = (q < 2) ? PAIR_A[p] : PAIR_B[p];
        if (jm >= 0) {
            int ocb = (q & 1) * 4;
            unsigned short* hp = h0u + ((size_t)b * CIN + jm * 8 + ocb) * T1 + t0 + tb + n;
#pragma unroll
            for (int r = 0; r < 4; ++r) {
                float v = acc[r] + b0[jm * 8 + ocb + r];
                v = (v >= 0.f) ? v : alpha * v;
                hp[(size_t)r * T1] = (unsigned short)bfround(v);
            }
        }
    }

    // ---- shortcut: tiles ji = jo*2+ns, round-robin over waves ----
    for (int ji = w; ji < 50; ji += 4) {
        int jo = ji >> 1, ns = ji & 1;
        int offj = NBR_OFF[jo], deg = NBR_OFF[jo + 1] - offj;
        int fb = FBS[jo], nsf = NSF[jo];
        int row = 32 * ns + 2 * n + 1;
        char* rb = (char*)xs + row * XROWB;
        int sw = xswz(row);
        f32x4 acc = {0.f, 0.f, 0.f, 0.f};
        bf16x8 a = *(const bf16x8*)(wAs + ((size_t)fb * 64 + lane) * 8);
        int ni0 = (q < deg) ? q : deg - 1;
        bf16x8 bv = *(const bf16x8*)(rb + ((NBR[offj + ni0] * 16) ^ sw));
        for (int mf = 0; mf < nsf; ++mf) {
            int mfn = (mf + 1 < nsf) ? mf + 1 : mf;
            bf16x8 an = *(const bf16x8*)(wAs + ((size_t)(fb + mfn) * 64 + lane) * 8);
            int c8 = mfn * 4 + q;
            int ni = (c8 < deg) ? c8 : deg - 1;
            bf16x8 bn = *(const bf16x8*)(rb + ((NBR[offj + ni] * 16) ^ sw));
            acc = __builtin_amdgcn_mfma_f32_16x16x32_bf16(a, bv, acc, 0, 0, 0);
            a = an; bv = bn;
        }
        unsigned short* sp = sbu + ((size_t)b * COUTC + jo * 16 + q * 4) * TT2 + (t0 >> 1) + ns * 16 + n;
#pragma unroll
        for (int r = 0; r < 4; ++r) {
            float v = acc[r] + bsc[jo * 16 + q * 4 + r];
            sp[(size_t)r * TT2] = (unsigned short)bfround(v);
        }
    }
}

// ------- Kernel B: conv1 via MFMA + GN partials, B-prefetch pipelined ------------
// grid (64, 16), block 256 (4 waves x 16 t2).
__global__ __launch_bounds__(256) void conv1_mfma(
    const unsigned* __restrict__ h0b, const unsigned short* __restrict__ wA,
    const float* __restrict__ b1, unsigned short* __restrict__ h1u,
    float* __restrict__ part)
{
    __shared__ unsigned short xs[(65 + 64) * CPAD];
    __shared__ float biasl[COUTC];
    __shared__ int   nbrl[145];
    const int b   = blockIdx.y;
    const int t20 = blockIdx.x * 64;
    const int tid = threadIdx.x;

    for (int i = tid; i < 145; i += 256) nbrl[i] = NBR[i];
    for (int i = tid; i < COUTC; i += 256) biasl[i] = b1[i];

    const unsigned* hb = h0b + (size_t)b * CIN * (T1 / 2);
    for (int e = tid; e < CIN * 65; e += 256) {
        int c = e / 65, i = e - c * 65;
        int gi = t20 - 1 + i; if (gi < 0) gi = 0;
        unsigned u = hb[(size_t)c * (T1 / 2) + gi];
        xs[i * CPAD + c] = (unsigned short)(u >> 16);
        if (i > 0)
            xs[(65 + i - 1) * CPAD + c] = (unsigned short)(u & 0xFFFF);
    }
    __syncthreads();

    const int w = tid >> 6, lane = tid & 63;
    const int q = lane >> 4, n = lane & 15;
    const int t2l = w * 16 + n;
    const int t2g = t20 + t2l;

    for (int jo = 0; jo < NJ; ++jo) {
        const int off = NBR_OFF[jo];
        const int deg = NBR_OFF[jo + 1] - off;
        const int fb  = FBASE[jo];
        const int nmf = NMF[jo];
        f32x4 acc = {0.f, 0.f, 0.f, 0.f};

        bf16x8 a = *(const bf16x8*)(wA + ((size_t)fb * 64 + lane) * 8);
        int tp0 = (q >= 2 * deg) ? 2 : ((q >= deg) ? 1 : 0);
        int ni0 = q - tp0 * deg;
        bf16x8 bv = *(const bf16x8*)(xs + ((tp0 == 1) ? 65 * CPAD : 0)
                                       + (t2l + (tp0 >> 1)) * CPAD + nbrl[off + ni0] * 8);
        for (int mf = 0; mf < nmf; ++mf) {
            int mfn = (mf + 1 < nmf) ? mf + 1 : mf;
            bf16x8 an = *(const bf16x8*)(wA + ((size_t)(fb + mfn) * 64 + lane) * 8);
            int c8 = mfn * 4 + q;
            int tp = (c8 >= 2 * deg) ? 2 : ((c8 >= deg) ? 1 : 0);
            int ni = c8 - tp * deg;
            if (c8 >= 3 * deg) { tp = 0; ni = 0; }
            bf16x8 bn = *(const bf16x8*)(xs + ((tp == 1) ? 65 * CPAD : 0)
                                           + (t2l + (tp >> 1)) * CPAD + nbrl[off + ni] * 8);
            acc = __builtin_amdgcn_mfma_f32_16x16x32_bf16(a, bv, acc, 0, 0, 0);
            a = an; bv = bn;
        }

        float s = 0.f, ss = 0.f;
        unsigned short* hout = h1u + ((size_t)b * COUTC + jo * 16) * TT2 + t2g;
#pragma unroll
        for (int r = 0; r < 4; ++r) {
            int oc = q * 4 + r;
            float v = acc[r] + biasl[jo * 16 + oc];
            s += v; ss += v * v;
            hout[(size_t)oc * TT2] = (unsigned short)bfround(v);
        }
        for (int o2 = 1; o2 < 32; o2 <<= 1) {
            s  += __shfl_xor(s, o2, 64);
            ss += __shfl_xor(ss, o2, 64);
        }
        if ((lane & 31) == 0) {
            int half = lane >> 5;
            size_t o = ((((size_t)b * 50 + jo * 2 + half) * 64 + blockIdx.x) * 4 + w) * 2;
            part[o] = s; part[o + 1] = ss;
        }
    }
}

// ------- finalize stats ----------------------------------------------------------
__global__ __launch_bounds__(256) void gn_final2(const float* __restrict__ part,
                                                 float* __restrict__ stats)
{
    const int bg = blockIdx.x;
    const int b = bg / NGROUP, g = bg % NGROUP;
    float s = 0.f, ss = 0.f;
    for (int k = threadIdx.x; k < 5 * 256; k += 256) {
        int sb = k >> 8, slot = k & 255;
        size_t o = (((size_t)b * 50 + g * 5 + sb) * 256 + slot) * 2;
        s += part[o]; ss += part[o + 1];
    }
    for (int o2 = 32; o2; o2 >>= 1) {
        s  += __shfl_down(s, o2, 64);
        ss += __shfl_down(ss, o2, 64);
    }
    __shared__ float rs[4], rss[4];
    const int lane = threadIdx.x & 63, wv = threadIdx.x >> 6;
    if (lane == 0) { rs[wv] = s; rss[wv] = ss; }
    __syncthreads();
    if (threadIdx.x == 0) {
        float S  = rs[0] + rs[1] + rs[2] + rs[3];
        float SS = rss[0] + rss[1] + rss[2] + rss[3];
        const float invN = 1.0f / (float)(CPG * TT2);
        float mean = S * invN;
        float var  = SS * invN - mean * mean;
        stats[bg * 2]     = mean;
        stats[bg * 2 + 1] = rsqrtf(var + 1e-5f);
    }
}

// ------- per-(b,ch) GN coefficients ----------------------------------------------
__global__ void gn_coef(const float* __restrict__ stats, const float* __restrict__ gamma,
                        const float* __restrict__ beta, float* __restrict__ AB)
{
    int idx = blockIdx.x * 256 + threadIdx.x;
    if (idx < BATCH * COUTC) {
        int b = idx / COUTC; int ch = idx - b * COUTC;
        int g = ch / CPG;
        float m = stats[(b * NGROUP + g) * 2];
        float r = stats[(b * NGROUP + g) * 2 + 1];
        float A = r * gamma[ch];
        AB[(size_t)idx * 2]     = A;
        AB[(size_t)idx * 2 + 1] = beta[ch] - m * A;
    }
}

// ------- Kernel E: streaming GN-apply + add s + pool + PReLU ---------------------
__global__ __launch_bounds__(256) void final2pb(
    const unsigned* __restrict__ h1b, const unsigned* __restrict__ sb,
    const float* __restrict__ AB, const float* __restrict__ a1,
    float* __restrict__ outb)
{
    const int n     = blockIdx.y >> 1;
    const int chalf = blockIdx.y & 1;
    const int b     = blockIdx.z;
    const int tid   = threadIdx.x;
    const int t0    = (blockIdx.x * 256 + tid) * 4;

    int js[2];
    js[0] = PAIR_A[n];
    const int jb = PAIR_B[n];
    const int L = (jb >= 0) ? 2 : 1;
    js[1] = (jb >= 0) ? jb : js[0];

    __shared__ float Al[2][8], Bl[2][8];
    if (tid < 16) {
        int ji = tid >> 3, c8 = tid & 7;
        int ch = js[ji] * 16 + chalf * 8 + c8;
        Al[ji][c8] = AB[((size_t)b * COUTC + ch) * 2];
        Bl[ji][c8] = AB[((size_t)b * COUTC + ch) * 2 + 1];
    }
    __syncthreads();

    const float alpha = a1[0];
    const float invL  = (L == 2) ? 0.5f : 1.0f;

    float acc[8][4];
#pragma unroll
    for (int c = 0; c < 8; ++c)
#pragma unroll
        for (int i = 0; i < 4; ++i) acc[c][i] = 0.f;

    for (int ji = 0; ji < L; ++ji) {
        const int jc0 = js[ji] * 16 + chalf * 8;
#pragma unroll
        for (int c = 0; c < 8; ++c) {
            size_t rowoff = ((size_t)b * COUTC + jc0 + c) * (TT2 / 2) + t0 / 2;
            uint2 hv = *(const uint2*)(h1b + rowoff);
            uint2 sv = *(const uint2*)(sb + rowoff);
            float A = Al[ji][c], Bc = Bl[ji][c];
            acc[c][0] += bflo(hv.x) * A + Bc + bflo(sv.x);
            acc[c][1] += bfhi(hv.x) * A + Bc + bfhi(sv.x);
            acc[c][2] += bflo(hv.y) * A + Bc + bflo(sv.y);
            acc[c][3] += bfhi(hv.y) * A + Bc + bfhi(sv.y);
        }
    }

    float* ob = outb + ((size_t)b * 224 + n * 16 + chalf * 8) * TT2 + t0;
#pragma unroll
    for (int c = 0; c < 8; ++c) {
        float4 o;
#pragma unroll
        for (int i = 0; i < 4; ++i) {
            float v = acc[c][i] * invL;
            ((float*)&o)[i] = (v >= 0.f) ? v : alpha * v;
        }
        *(float4*)(ob + (size_t)c * TT2) = o;
    }
}

extern "C" void kernel_launch(void* const* d_in, const int* in_sizes, int n_in,
                              void* d_out, int out_size, void* d_ws, size_t ws_size,
                              hipStream_t stream) {
    const float* x     = (const float*)d_in[0];
    const float* w0    = (const float*)d_in[1];
    const float* b0    = (const float*)d_in[2];
    const float* a0    = (const float*)d_in[3];
    const float* w1    = (const float*)d_in[4];
    const float* b1    = (const float*)d_in[5];
    const float* gamma = (const float*)d_in[6];
    const float* beta  = (const float*)d_in[7];
    const float* wsc   = (const float*)d_in[8];
    const float* bsc   = (const float*)d_in[9];
    const float* a1    = (const float*)d_in[10];
    float* out = (float*)d_out;

    unsigned short* h0u = (unsigned short*)d_ws;                 // 26.2M u16
    unsigned short* sbu = h0u + (size_t)BATCH * CIN * T1;        // 26.2M u16
    unsigned short* h1u = sbu + (size_t)BATCH * COUTC * TT2;     // 26.2M u16
    unsigned short* wA1 = h1u + (size_t)BATCH * COUTC * TT2;     // 117*512
    unsigned short* wA0p = wA1 + (size_t)NFRAG * 512;            // 76*512
    unsigned short* wAsp = wA0p + (size_t)76 * 512;              // 44*512
    float* part  = (float*)(wAsp + (size_t)44 * 512);            // 16*50*256*2
    float* stats = part + (size_t)BATCH * 50 * 256 * 2;
    float* AB    = stats + BATCH * NGROUP * 2;

    wprep1<<<dim3(NFRAG), 256, 0, stream>>>(w1, wA1);
    wprep0<<<dim3(76), 256, 0, stream>>>(w0, wA0p);
    wprepS<<<dim3(44), 256, 0, stream>>>(wsc, wAsp);
    conv0s_mfma<<<dim3(T1 / 64, BATCH), 256, 0, stream>>>(x, wA0p, wAsp, b0, a0, bsc, h0u, sbu);
    conv1_mfma<<<dim3(TT2 / 64, BATCH), 256, 0, stream>>>((const unsigned*)h0u, wA1, b1, h1u, part);
    gn_final2<<<dim3(BATCH * NGROUP), 256, 0, stream>>>(part, stats);
    gn_coef<<<dim3(25), 256, 0, stream>>>(stats, gamma, beta, AB);
    final2pb<<<dim3(TT2 / 1024, NPOOL * 2, BATCH), 256, 0, stream>>>((const unsigned*)h1u,
                                                                     (const unsigned*)sbu, AB, a1, out);
}

// Round 11
// 283.192 us; speedup vs baseline: 1.1412x; 1.1151x over previous
//
#include <hip/hip_runtime.h>

#define BATCH 16
#define CIN   200
#define T1    8192
#define COUTC 400
#define TT2   4096
#define NJ    25
#define NGROUP 10
#define CPG   40
#define NPOOL 14
#define NFRAG 117
#define XROWB 512      // bytes per LDS row (swizzle-safe)

typedef __attribute__((ext_vector_type(8))) short bf16x8;
typedef __attribute__((ext_vector_type(4))) float f32x4;

__constant__ int NBR_OFF[NJ + 1] = {0,8,14,18,21,29,35,39,42,50,56,63,72,80,85,94,101,106,110,113,122,129,134,138,141,145};
__constant__ int NBR[145] = {
 0,1,2,4,5,8,9,24,
 0,1,2,3,4,8,
 0,1,2,3,
 1,2,3,
 0,1,4,5,6,8,9,24,
 0,4,5,6,7,8,
 4,5,6,7,
 5,6,7,
 0,1,4,5,8,9,10,24,
 0,4,8,9,10,11,
 8,9,10,11,12,14,19,
 9,10,11,12,13,14,15,19,20,
 10,11,12,13,14,15,19,20,
 11,12,13,14,19,
 10,11,12,13,14,15,16,19,20,
 11,12,14,15,16,17,19,
 14,15,16,17,18,
 15,16,17,18,
 16,17,18,
 10,11,12,13,14,15,19,20,21,
 11,12,14,19,20,21,22,
 19,20,21,22,23,
 20,21,22,23,
 21,22,23,
 0,4,8,24};
__constant__ int PAIR_A[NPOOL] = {0,2,4,6,8,10,12,14,15,17,19,20,22,24};
__constant__ int PAIR_B[NPOOL] = {1,3,5,7,9,11,13,-1,16,18,-1,21,23,-1};
// conv1 fragment tables
__constant__ int NMF[NJ]   = {6,5,3,3,6,5,3,3,6,5,6,7,6,4,7,6,4,3,3,7,6,4,3,3,3};
__constant__ int FBASE[NJ] = {0,6,11,14,17,23,28,31,34,40,45,51,58,64,68,75,81,85,88,91,98,104,108,111,114};
__constant__ int FRAG_JO[NFRAG] = {
 0,0,0,0,0,0, 1,1,1,1,1, 2,2,2, 3,3,3, 4,4,4,4,4,4, 5,5,5,5,5, 6,6,6, 7,7,7,
 8,8,8,8,8,8, 9,9,9,9,9, 10,10,10,10,10,10, 11,11,11,11,11,11,11, 12,12,12,12,12,12,
 13,13,13,13, 14,14,14,14,14,14,14, 15,15,15,15,15,15, 16,16,16,16, 17,17,17, 18,18,18,
 19,19,19,19,19,19,19, 20,20,20,20,20,20, 21,21,21,21, 22,22,22, 23,23,23, 24,24,24};
// conv0 pair-union tables
__constant__ int PUOFF[15] = {0,9,13,22,26,35,45,53,62,70,74,83,91,95,99};
__constant__ int PU[99] = {
 0,1,2,3,4,5,8,9,24,
 0,1,2,3,
 0,1,4,5,6,7,8,9,24,
 4,5,6,7,
 0,1,4,5,8,9,10,11,24,
 8,9,10,11,12,13,14,15,19,20,
 10,11,12,13,14,15,19,20,
 10,11,12,13,14,15,16,19,20,
 11,12,14,15,16,17,18,19,
 15,16,17,18,
 10,11,12,13,14,15,19,20,21,
 11,12,14,19,20,21,22,23,
 20,21,22,23,
 0,4,8,24};
__constant__ int PNMF[NPOOL] = {7,3,7,3,7,8,6,7,6,3,7,6,3,3};
__constant__ int FB0[NPOOL]  = {0,7,10,17,20,27,35,41,48,54,57,64,70,73};  // total 76
__constant__ int FRAG_P[76] = {
 0,0,0,0,0,0,0, 1,1,1, 2,2,2,2,2,2,2, 3,3,3, 4,4,4,4,4,4,4, 5,5,5,5,5,5,5,5,
 6,6,6,6,6,6, 7,7,7,7,7,7,7, 8,8,8,8,8,8, 9,9,9, 10,10,10,10,10,10,10,
 11,11,11,11,11,11, 12,12,12, 13,13,13};
// shortcut fragment tables
__constant__ int NSF[NJ] = {2,2,1,1,2,2,1,1,2,2,2,3,2,2,3,2,2,1,1,3,2,2,1,1,1};
__constant__ int FBS[NJ] = {0,2,4,5,6,8,10,11,12,14,16,18,21,23,25,28,30,32,33,34,37,39,41,42,43}; // total 44
__constant__ int FRAG_SJ[44] = {
 0,0, 1,1, 2, 3, 4,4, 5,5, 6, 7, 8,8, 9,9, 10,10, 11,11,11, 12,12, 13,13,
 14,14,14, 15,15, 16,16, 17, 18, 19,19,19, 20,20, 21,21, 22, 23, 24};

// ---- bf16 helpers ----
__device__ __forceinline__ unsigned bfround(float f) {
    unsigned u = __builtin_bit_cast(unsigned, f);
    return (u + 0x7FFFu + ((u >> 16) & 1u)) >> 16;
}
__device__ __forceinline__ float bflo(unsigned u) { return __builtin_bit_cast(float, u << 16); }
__device__ __forceinline__ float bfhi(unsigned u) { return __builtin_bit_cast(float, u & 0xFFFF0000u); }
__device__ __forceinline__ int xswz(int row) { return ((row + (row >> 3)) & 7) << 4; }

// ------- prepack conv1 weights --------------------------------------------------
__global__ void wprep1(const float* __restrict__ w1, unsigned short* __restrict__ wA)
{
    const int f  = blockIdx.x;
    const int jo = FRAG_JO[f];
    const int mf = f - FBASE[jo];
    const int off = NBR_OFF[jo];
    const int deg = NBR_OFF[jo + 1] - off;
    for (int e = threadIdx.x; e < 512; e += 256) {
        int lane = e >> 3, j = e & 7;
        int m = lane & 15, kb = lane >> 4;
        int c8 = mf * 4 + kb;
        float v = 0.f;
        if (c8 < 3 * deg) {
            int tap = (c8 >= 2 * deg) ? 2 : ((c8 >= deg) ? 1 : 0);
            int nbr_i = c8 - tap * deg;
            int ci = NBR[off + nbr_i] * 8 + j;
            v = w1[(size_t)(jo * 16 + m) * 600 + ci * 3 + tap];
        }
        wA[(size_t)f * 512 + e] = (unsigned short)bfround(v);
    }
}

// ------- prepack conv0 pair weights ----------------------------------------------
__global__ void wprep0(const float* __restrict__ w0, unsigned short* __restrict__ wA)
{
    const int f  = blockIdx.x;
    const int p  = FRAG_P[f];
    const int mf = f - FB0[p];
    const int puo = PUOFF[p];
    const int u   = PUOFF[p + 1] - puo;
    for (int e = threadIdx.x; e < 512; e += 256) {
        int lane = e >> 3, j = e & 7;
        int m = lane & 15, kb = lane >> 4;
        int c8 = mf * 4 + kb;
        int jm = (m < 8) ? PAIR_A[p] : PAIR_B[p];
        float v = 0.f;
        if (c8 < 3 * u && jm >= 0) {
            int tap = (c8 >= 2 * u) ? 2 : ((c8 >= u) ? 1 : 0);
            int ni  = c8 - tap * u;
            int nbr = PU[puo + ni];
            int offj = NBR_OFF[jm], degj = NBR_OFF[jm + 1] - offj;
            bool mem = false;
            for (int s = 0; s < degj; ++s) mem = mem || (NBR[offj + s] == nbr);
            if (mem) {
                int ci = nbr * 8 + j;
                v = w0[(size_t)(jm * 8 + (m & 7)) * 600 + ci * 3 + tap];
            }
        }
        wA[(size_t)f * 512 + e] = (unsigned short)bfround(v);
    }
}

// ------- prepack shortcut weights ------------------------------------------------
__global__ void wprepS(const float* __restrict__ wsc, unsigned short* __restrict__ wA)
{
    const int f  = blockIdx.x;
    const int jo = FRAG_SJ[f];
    const int mf = f - FBS[jo];
    const int off = NBR_OFF[jo];
    const int deg = NBR_OFF[jo + 1] - off;
    for (int e = threadIdx.x; e < 512; e += 256) {
        int lane = e >> 3, j = e & 7;
        int m = lane & 15, kb = lane >> 4;
        int c8 = mf * 4 + kb;
        float v = 0.f;
        if (c8 < deg) {
            int ci = NBR[off + c8] * 8 + j;
            v = wsc[(size_t)(jo * 16 + m) * 200 + ci];
        }
        wA[(size_t)f * 512 + e] = (unsigned short)bfround(v);
    }
}

// ------- Kernel T1: x fp32 [c][t] -> xT bf16 [t][c]  -----------------------------
// grid (128, 16), block 256.  LDS 64 rows x 512 B.
__global__ __launch_bounds__(256) void xtr_k(const float* __restrict__ x,
                                             unsigned short* __restrict__ xT)
{
    __shared__ __align__(16) unsigned short ts[64 * 256];
    const int b = blockIdx.y, t0 = blockIdx.x * 64, tid = threadIdx.x;
    const float* xb = x + (size_t)b * CIN * T1;

    for (int e = tid; e < CIN * 16; e += 256) {
        int c = e >> 4, k = e & 15;
        float4 v = *(const float4*)(xb + (size_t)c * T1 + t0 + 4 * k);
        int r0 = 4 * k, cb = 2 * c;
        *(unsigned short*)((char*)ts + (r0 + 0) * XROWB + (cb ^ xswz(r0 + 0))) = (unsigned short)bfround(v.x);
        *(unsigned short*)((char*)ts + (r0 + 1) * XROWB + (cb ^ xswz(r0 + 1))) = (unsigned short)bfround(v.y);
        *(unsigned short*)((char*)ts + (r0 + 2) * XROWB + (cb ^ xswz(r0 + 2))) = (unsigned short)bfround(v.z);
        *(unsigned short*)((char*)ts + (r0 + 3) * XROWB + (cb ^ xswz(r0 + 3))) = (unsigned short)bfround(v.w);
    }
    __syncthreads();

    unsigned short* xo = xT + ((size_t)b * T1 + t0) * CIN;
    for (int e = tid; e < 64 * 25; e += 256) {
        int row = e / 25, k = e - row * 25;
        uint4 u = *(const uint4*)((char*)ts + row * XROWB + ((16 * k) ^ xswz(row)));
        *(uint4*)(xo + (size_t)row * CIN + 8 * k) = u;
    }
}

// ------- Kernel T2: h0 bf16 [c][t] -> h0T bf16 [t][c] ----------------------------
// grid (128, 16), block 256.
__global__ __launch_bounds__(256) void h0tr_k(const unsigned short* __restrict__ h0,
                                              unsigned short* __restrict__ h0T)
{
    __shared__ __align__(16) unsigned short ts[64 * 256];
    const int b = blockIdx.y, t0 = blockIdx.x * 64, tid = threadIdx.x;
    const unsigned short* hb = h0 + (size_t)b * CIN * T1;

    for (int e = tid; e < CIN * 16; e += 256) {
        int c = e >> 4, k = e & 15;
        uint2 u = *(const uint2*)(hb + (size_t)c * T1 + t0 + 4 * k);
        int r0 = 4 * k, cb = 2 * c;
        *(unsigned short*)((char*)ts + (r0 + 0) * XROWB + (cb ^ xswz(r0 + 0))) = (unsigned short)(u.x & 0xFFFF);
        *(unsigned short*)((char*)ts + (r0 + 1) * XROWB + (cb ^ xswz(r0 + 1))) = (unsigned short)(u.x >> 16);
        *(unsigned short*)((char*)ts + (r0 + 2) * XROWB + (cb ^ xswz(r0 + 2))) = (unsigned short)(u.y & 0xFFFF);
        *(unsigned short*)((char*)ts + (r0 + 3) * XROWB + (cb ^ xswz(r0 + 3))) = (unsigned short)(u.y >> 16);
    }
    __syncthreads();

    unsigned short* xo = h0T + ((size_t)b * T1 + t0) * CIN;
    for (int e = tid; e < 64 * 25; e += 256) {
        int row = e / 25, k = e - row * 25;
        uint4 u = *(const uint4*)((char*)ts + row * XROWB + ((16 * k) ^ xswz(row)));
        *(uint4*)(xo + (size_t)row * CIN + 8 * k) = u;
    }
}

// ------- Kernel A: conv0 + PReLU + shortcut via MFMA (stages xT rows) ------------
// grid (128, 16), block 256 (4 waves). LDS 66 rows x 512 B = 33.8 KB.
__global__ __launch_bounds__(256) void conv0s_mfma(
    const unsigned short* __restrict__ xT, const unsigned short* __restrict__ wA0,
    const unsigned short* __restrict__ wAs, const float* __restrict__ b0,
    const float* __restrict__ a0, const float* __restrict__ bsc,
    unsigned short* __restrict__ h0u, unsigned short* __restrict__ sbu)
{
    __shared__ __align__(16) unsigned short xs[66 * 256];
    const int b   = blockIdx.y;
    const int t0  = blockIdx.x * 64;
    const int tid = threadIdx.x;

    const unsigned short* xTb = xT + (size_t)b * T1 * CIN;
    for (int e = tid; e < 66 * 25; e += 256) {
        int row = e / 25, k = e - row * 25;
        int t = t0 - 1 + row;
        t = (t < 0) ? 1 : ((t >= T1) ? (2 * T1 - 2 - t) : t);
        uint4 u = *(const uint4*)(xTb + (size_t)t * CIN + 8 * k);
        *(uint4*)((char*)xs + row * XROWB + ((16 * k) ^ xswz(row))) = u;
    }
    __syncthreads();

    const int w = tid >> 6, lane = tid & 63;
    const int q = lane >> 4, n = lane & 15;
    const float alpha = a0[0];

    // ---- conv0: wave w owns t-subtile [t0+16w, t0+16w+16) ----
    const int tb = w * 16;
    for (int p = 0; p < NPOOL; ++p) {
        const int puo = PUOFF[p];
        const int u   = PUOFF[p + 1] - puo;
        const int fb  = FB0[p], nmf = PNMF[p];
        f32x4 acc = {0.f, 0.f, 0.f, 0.f};
        bf16x8 a = *(const bf16x8*)(wA0 + ((size_t)fb * 64 + lane) * 8);
        int row0 = tb + n;
        bf16x8 bv = *(const bf16x8*)((char*)xs + row0 * XROWB + ((PU[puo + q] * 16) ^ xswz(row0)));
        for (int mf = 0; mf < nmf; ++mf) {
            int mfn = (mf + 1 < nmf) ? mf + 1 : mf;
            bf16x8 an = *(const bf16x8*)(wA0 + ((size_t)(fb + mfn) * 64 + lane) * 8);
            int c8 = mfn * 4 + q;
            int tp = (c8 >= 2 * u) ? 2 : ((c8 >= u) ? 1 : 0);
            int ni = c8 - tp * u;
            if (c8 >= 3 * u) { tp = 0; ni = 0; }
            int rw = tb + n + tp;
            bf16x8 bn = *(const bf16x8*)((char*)xs + rw * XROWB + ((PU[puo + ni] * 16) ^ xswz(rw)));
            acc = __builtin_amdgcn_mfma_f32_16x16x32_bf16(a, bv, acc, 0, 0, 0);
            a = an; bv = bn;
        }
        int jm = (q < 2) ? PAIR_A[p] : PAIR_B[p];
        if (jm >= 0) {
            int ocb = (q & 1) * 4;
            unsigned short* hp = h0u + ((size_t)b * CIN + jm * 8 + ocb) * T1 + t0 + tb + n;
#pragma unroll
            for (int r = 0; r < 4; ++r) {
                float v = acc[r] + b0[jm * 8 + ocb + r];
                v = (v >= 0.f) ? v : alpha * v;
                hp[(size_t)r * T1] = (unsigned short)bfround(v);
            }
        }
    }

    // ---- shortcut: tiles ji = jo*2+ns, round-robin over waves ----
    for (int ji = w; ji < 50; ji += 4) {
        int jo = ji >> 1, ns = ji & 1;
        int offj = NBR_OFF[jo], deg = NBR_OFF[jo + 1] - offj;
        int fb = FBS[jo], nsf = NSF[jo];
        int row = 32 * ns + 2 * n + 1;
        char* rb = (char*)xs + row * XROWB;
        int sw = xswz(row);
        f32x4 acc = {0.f, 0.f, 0.f, 0.f};
        bf16x8 a = *(const bf16x8*)(wAs + ((size_t)fb * 64 + lane) * 8);
        int ni0 = (q < deg) ? q : deg - 1;
        bf16x8 bv = *(const bf16x8*)(rb + ((NBR[offj + ni0] * 16) ^ sw));
        for (int mf = 0; mf < nsf; ++mf) {
            int mfn = (mf + 1 < nsf) ? mf + 1 : mf;
            bf16x8 an = *(const bf16x8*)(wAs + ((size_t)(fb + mfn) * 64 + lane) * 8);
            int c8 = mfn * 4 + q;
            int ni = (c8 < deg) ? c8 : deg - 1;
            bf16x8 bn = *(const bf16x8*)(rb + ((NBR[offj + ni] * 16) ^ sw));
            acc = __builtin_amdgcn_mfma_f32_16x16x32_bf16(a, bv, acc, 0, 0, 0);
            a = an; bv = bn;
        }
        unsigned short* sp = sbu + ((size_t)b * COUTC + jo * 16 + q * 4) * TT2 + (t0 >> 1) + ns * 16 + n;
#pragma unroll
        for (int r = 0; r < 4; ++r) {
            float v = acc[r] + bsc[jo * 16 + q * 4 + r];
            sp[(size_t)r * TT2] = (unsigned short)bfround(v);
        }
    }
}

// ------- Kernel B: conv1 via MFMA + GN partials (stages h0T rows) ----------------
// grid (128, 16), block 256 (4 waves = 2 t2-cols x 2 joint-halves). LDS 65x512B.
__global__ __launch_bounds__(256) void conv1_mfma(
    const unsigned short* __restrict__ h0T, const unsigned short* __restrict__ wA,
    const float* __restrict__ b1, unsigned short* __restrict__ h1u,
    float* __restrict__ part)
{
    __shared__ __align__(16) unsigned short xs[65 * 256];
    const int b   = blockIdx.y;
    const int t20 = blockIdx.x * 32;
    const int tid = threadIdx.x;

    const unsigned short* hTb = h0T + (size_t)b * T1 * CIN;
    for (int e = tid; e < 65 * 25; e += 256) {
        int row = e / 25, k = e - row * 25;
        int p = 2 * t20 - 1 + row;
        if (p < 0) p = 1;
        uint4 u = *(const uint4*)(hTb + (size_t)p * CIN + 8 * k);
        *(uint4*)((char*)xs + row * XROWB + ((16 * k) ^ xswz(row))) = u;
    }
    __syncthreads();

    const int w = tid >> 6, lane = tid & 63;
    const int q = lane >> 4, n = lane & 15;
    const int sub = w & 1, jh = w >> 1;
    const int t2l = sub * 16 + n;
    const int t2g = t20 + t2l;
    const int j0 = jh ? 13 : 0, j1 = jh ? 25 : 13;

    for (int jo = j0; jo < j1; ++jo) {
        const int off = NBR_OFF[jo];
        const int deg = NBR_OFF[jo + 1] - off;
        const int fb  = FBASE[jo];
        const int nmf = NMF[jo];
        f32x4 acc = {0.f, 0.f, 0.f, 0.f};

        bf16x8 a = *(const bf16x8*)(wA + ((size_t)fb * 64 + lane) * 8);
        int tp0 = (q >= 2 * deg) ? 2 : ((q >= deg) ? 1 : 0);
        int ni0 = q - tp0 * deg;
        int row0 = 2 * t2l + tp0;
        bf16x8 bv = *(const bf16x8*)((char*)xs + row0 * XROWB + ((NBR[off + ni0] * 16) ^ xswz(row0)));
        for (int mf = 0; mf < nmf; ++mf) {
            int mfn = (mf + 1 < nmf) ? mf + 1 : mf;
            bf16x8 an = *(const bf16x8*)(wA + ((size_t)(fb + mfn) * 64 + lane) * 8);
            int c8 = mfn * 4 + q;
            int tp = (c8 >= 2 * deg) ? 2 : ((c8 >= deg) ? 1 : 0);
            int ni = c8 - tp * deg;
            if (c8 >= 3 * deg) { tp = 0; ni = 0; }
            int rw = 2 * t2l + tp;
            bf16x8 bn = *(const bf16x8*)((char*)xs + rw * XROWB + ((NBR[off + ni] * 16) ^ xswz(rw)));
            acc = __builtin_amdgcn_mfma_f32_16x16x32_bf16(a, bv, acc, 0, 0, 0);
            a = an; bv = bn;
        }

        float s = 0.f, ss = 0.f;
        unsigned short* hout = h1u + ((size_t)b * COUTC + jo * 16) * TT2 + t2g;
#pragma unroll
        for (int r = 0; r < 4; ++r) {
            int oc = q * 4 + r;
            float v = acc[r] + b1[jo * 16 + oc];
            s += v; ss += v * v;
            hout[(size_t)oc * TT2] = (unsigned short)bfround(v);
        }
        for (int o2 = 1; o2 < 32; o2 <<= 1) {
            s  += __shfl_xor(s, o2, 64);
            ss += __shfl_xor(ss, o2, 64);
        }
        if ((lane & 31) == 0) {
            int half = lane >> 5;
            size_t o = (((size_t)b * 50 + jo * 2 + half) * 256 + blockIdx.x * 2 + sub) * 2;
            part[o] = s; part[o + 1] = ss;
        }
    }
}

// ------- finalize stats ----------------------------------------------------------
__global__ __launch_bounds__(256) void gn_final2(const float* __restrict__ part,
                                                 float* __restrict__ stats)
{
    const int bg = blockIdx.x;
    const int b = bg / NGROUP, g = bg % NGROUP;
    float s = 0.f, ss = 0.f;
    for (int k = threadIdx.x; k < 5 * 256; k += 256) {
        int sb = k >> 8, slot = k & 255;
        size_t o = (((size_t)b * 50 + g * 5 + sb) * 256 + slot) * 2;
        s += part[o]; ss += part[o + 1];
    }
    for (int o2 = 32; o2; o2 >>= 1) {
        s  += __shfl_down(s, o2, 64);
        ss += __shfl_down(ss, o2, 64);
    }
    __shared__ float rs[4], rss[4];
    const int lane = threadIdx.x & 63, wv = threadIdx.x >> 6;
    if (lane == 0) { rs[wv] = s; rss[wv] = ss; }
    __syncthreads();
    if (threadIdx.x == 0) {
        float S  = rs[0] + rs[1] + rs[2] + rs[3];
        float SS = rss[0] + rss[1] + rss[2] + rss[3];
        const float invN = 1.0f / (float)(CPG * TT2);
        float mean = S * invN;
        float var  = SS * invN - mean * mean;
        stats[bg * 2]     = mean;
        stats[bg * 2 + 1] = rsqrtf(var + 1e-5f);
    }
}

// ------- per-(b,ch) GN coefficients ----------------------------------------------
__global__ void gn_coef(const float* __restrict__ stats, const float* __restrict__ gamma,
                        const float* __restrict__ beta, float* __restrict__ AB)
{
    int idx = blockIdx.x * 256 + threadIdx.x;
    if (idx < BATCH * COUTC) {
        int b = idx / COUTC; int ch = idx - b * COUTC;
        int g = ch / CPG;
        float m = stats[(b * NGROUP + g) * 2];
        float r = stats[(b * NGROUP + g) * 2 + 1];
        float A = r * gamma[ch];
        AB[(size_t)idx * 2]     = A;
        AB[(size_t)idx * 2 + 1] = beta[ch] - m * A;
    }
}

// ------- Kernel E: streaming GN-apply + add s + pool + PReLU ---------------------
__global__ __launch_bounds__(256) void final2pb(
    const unsigned* __restrict__ h1b, const unsigned* __restrict__ sb,
    const float* __restrict__ AB, const float* __restrict__ a1,
    float* __restrict__ outb)
{
    const int n     = blockIdx.y >> 1;
    const int chalf = blockIdx.y & 1;
    const int b     = blockIdx.z;
    const int tid   = threadIdx.x;
    const int t0    = (blockIdx.x * 256 + tid) * 4;

    int js[2];
    js[0] = PAIR_A[n];
    const int jb = PAIR_B[n];
    const int L = (jb >= 0) ? 2 : 1;
    js[1] = (jb >= 0) ? jb : js[0];

    __shared__ float Al[2][8], Bl[2][8];
    if (tid < 16) {
        int ji = tid >> 3, c8 = tid & 7;
        int ch = js[ji] * 16 + chalf * 8 + c8;
        Al[ji][c8] = AB[((size_t)b * COUTC + ch) * 2];
        Bl[ji][c8] = AB[((size_t)b * COUTC + ch) * 2 + 1];
    }
    __syncthreads();

    const float alpha = a1[0];
    const float invL  = (L == 2) ? 0.5f : 1.0f;

    float acc[8][4];
#pragma unroll
    for (int c = 0; c < 8; ++c)
#pragma unroll
        for (int i = 0; i < 4; ++i) acc[c][i] = 0.f;

    for (int ji = 0; ji < L; ++ji) {
        const int jc0 = js[ji] * 16 + chalf * 8;
#pragma unroll
        for (int c = 0; c < 8; ++c) {
            size_t rowoff = ((size_t)b * COUTC + jc0 + c) * (TT2 / 2) + t0 / 2;
            uint2 hv = *(const uint2*)(h1b + rowoff);
            uint2 sv = *(const uint2*)(sb + rowoff);
            float A = Al[ji][c], Bc = Bl[ji][c];
            acc[c][0] += bflo(hv.x) * A + Bc + bflo(sv.x);
            acc[c][1] += bfhi(hv.x) * A + Bc + bfhi(sv.x);
            acc[c][2] += bflo(hv.y) * A + Bc + bflo(sv.y);
            acc[c][3] += bfhi(hv.y) * A + Bc + bfhi(sv.y);
        }
    }

    float* ob = outb + ((size_t)b * 224 + n * 16 + chalf * 8) * TT2 + t0;
#pragma unroll
    for (int c = 0; c < 8; ++c) {
        float4 o;
#pragma unroll
        for (int i = 0; i < 4; ++i) {
            float v = acc[c][i] * invL;
            ((float*)&o)[i] = (v >= 0.f) ? v : alpha * v;
        }
        *(float4*)(ob + (size_t)c * TT2) = o;
    }
}

extern "C" void kernel_launch(void* const* d_in, const int* in_sizes, int n_in,
                              void* d_out, int out_size, void* d_ws, size_t ws_size,
                              hipStream_t stream) {
    const float* x     = (const float*)d_in[0];
    const float* w0    = (const float*)d_in[1];
    const float* b0    = (const float*)d_in[2];
    const float* a0    = (const float*)d_in[3];
    const float* w1    = (const float*)d_in[4];
    const float* b1    = (const float*)d_in[5];
    const float* gamma = (const float*)d_in[6];
    const float* beta  = (const float*)d_in[7];
    const float* wsc   = (const float*)d_in[8];
    const float* bsc   = (const float*)d_in[9];
    const float* a1    = (const float*)d_in[10];
    float* out = (float*)d_out;

    const size_t NB = (size_t)BATCH * CIN * T1;   // 26,214,400 elements
    unsigned short* bufA = (unsigned short*)d_ws; // xT, later reused as h0T
    unsigned short* h0u  = bufA + NB;
    unsigned short* sbu  = h0u + NB;
    unsigned short* h1u  = sbu + NB;
    unsigned short* wA1  = h1u + NB;                              // 117*512
    unsigned short* wA0p = wA1 + (size_t)NFRAG * 512;             // 76*512
    unsigned short* wAsp = wA0p + (size_t)76 * 512;               // 44*512
    float* part  = (float*)(wAsp + (size_t)44 * 512);             // 16*50*256*2
    float* stats = part + (size_t)BATCH * 50 * 256 * 2;
    float* AB    = stats + BATCH * NGROUP * 2;

    wprep1<<<dim3(NFRAG), 256, 0, stream>>>(w1, wA1);
    wprep0<<<dim3(76), 256, 0, stream>>>(w0, wA0p);
    wprepS<<<dim3(44), 256, 0, stream>>>(wsc, wAsp);
    xtr_k<<<dim3(T1 / 64, BATCH), 256, 0, stream>>>(x, bufA);
    conv0s_mfma<<<dim3(T1 / 64, BATCH), 256, 0, stream>>>(bufA, wA0p, wAsp, b0, a0, bsc, h0u, sbu);
    h0tr_k<<<dim3(T1 / 64, BATCH), 256, 0, stream>>>(h0u, bufA);
    conv1_mfma<<<dim3(TT2 / 32, BATCH), 256, 0, stream>>>(bufA, wA1, b1, h1u, part);
    gn_final2<<<dim3(BATCH * NGROUP), 256, 0, stream>>>(part, stats);
    gn_coef<<<dim3(25), 256, 0, stream>>>(stats, gamma, beta, AB);
    final2pb<<<dim3(TT2 / 1024, NPOOL * 2, BATCH), 256, 0, stream>>>((const unsigned*)h1u,
                                                                     (const unsigned*)sbu, AB, a1, out);
}